// Round 4
// baseline (796.587 us; speedup 1.0000x reference)
//
#include <hip/hip_runtime.h>

#define NPER 4096
#define MS   1024
#define CIN  64
#define LCAP 384

typedef float  f32x4 __attribute__((ext_vector_type(4)));
typedef short  s16x8 __attribute__((ext_vector_type(8)));

// Exact d2 matching the numpy/XLA reference: per-component sub, rounded square,
// left-assoc sum. _rn forbids fma contraction -> bit-exact ball/argmax decisions.
__device__ __forceinline__ float d2_exact(float ax, float ay, float az,
                                          float bx, float by, float bz) {
  float dx = __fsub_rn(ax, bx);
  float dy = __fsub_rn(ay, by);
  float dz = __fsub_rn(az, bz);
  return __fadd_rn(__fadd_rn(__fmul_rn(dx, dx), __fmul_rn(dy, dy)), __fmul_rn(dz, dz));
}

// f32 -> bf16 (RNE) bit pattern
__device__ __forceinline__ unsigned short f2bf(float f) {
  unsigned b = __float_as_uint(f);
  return (unsigned short)((b + 0x7FFFu + ((b >> 16) & 1u)) >> 16);
}

template <int CTRL, int RMASK>
__device__ __forceinline__ unsigned long long dpp_max_step(unsigned long long k) {
  int hi = (int)(unsigned)(k >> 32);
  int lo = (int)(unsigned)(k & 0xFFFFFFFFull);
  int thi = __builtin_amdgcn_update_dpp(hi, hi, CTRL, RMASK, 0xF, false);
  int tlo = __builtin_amdgcn_update_dpp(lo, lo, CTRL, RMASK, 0xF, false);
  unsigned long long t =
      ((unsigned long long)(unsigned)thi << 32) | (unsigned)tlo;
  return t > k ? t : k;
}

__device__ __forceinline__ unsigned long long u64max(unsigned long long a,
                                                    unsigned long long b) {
  return a > b ? a : b;
}

// ---------------- FPS with exact cell pruning ------------------------------
// One block/graph, 256 threads. One-time: Morton counting-sort (512 cells) so
// each thread owns 16 spatially-contiguous points (regs) + tight bbox.
// Per iter: if lb2(s, bbox)*(1-1.2e-6) >= cached cell-max dist, the whole
// cell provably cannot change (dist only decreases; d2 >= lb2 >= bd >= dist_i)
// -> reuse cached max key. Else scalar update + exact u64 key recompute.
// Key = (dist_bits<<32) | (~orig & 0xFFF)<<12 | sortedpos: u64 max == max dist,
// ties -> lowest ORIGINAL index (== jnp.argmax first occurrence), sortedpos
// bits never decide between distinct points. Reduce identical to R2-proven:
// DPP butterfly -> lane63 write -> 1 barrier -> replicated 4-key tree.
__global__ __launch_bounds__(256) void fps_kernel(const float* __restrict__ pos,
                                                  int* __restrict__ idx_out) {
  const int b = blockIdx.x;
  const int t = threadIdx.x;
  __shared__ float4 s_pts[NPER];            // sorted: x,y,z, bits(tag)
  __shared__ unsigned s_hist[512];
  __shared__ unsigned s_scan[256];
  __shared__ float4 s_first;
  __shared__ __align__(16) unsigned long long s_red[2][4];
  const float* pb = pos + (size_t)b * NPER * 3;

  // ---- Phase A: load + Morton code + counting sort -----------------------
  float tx[16], ty[16], tz[16];
  int mo[16];
  s_hist[t] = 0u;
  s_hist[t + 256] = 0u;
  __syncthreads();
#pragma unroll
  for (int j = 0; j < 16; ++j) {
    const int i = t + j * 256;
    float X = pb[i * 3], Y = pb[i * 3 + 1], Z = pb[i * 3 + 2];
    tx[j] = X; ty[j] = Y; tz[j] = Z;
    int cx = min(7, max(0, (int)(X * 8.f)));
    int cy = min(7, max(0, (int)(Y * 8.f)));
    int cz = min(7, max(0, (int)(Z * 8.f)));
    int m = ((cx & 1) << 2) | ((cx & 2) << 4) | ((cx & 4) << 6)
          | ((cy & 1) << 1) | ((cy & 2) << 3) | ((cy & 4) << 5)
          | ((cz & 1)     ) | ((cz & 2) << 2) | ((cz & 4) << 4);
    mo[j] = m;
    atomicAdd(&s_hist[m], 1u);
    if (i == 0) s_first = make_float4(X, Y, Z, 0.f);
  }
  __syncthreads();
  const unsigned h0 = s_hist[2 * t], h1 = s_hist[2 * t + 1];
  const unsigned psum = h0 + h1;
  s_scan[t] = psum;
  __syncthreads();
  for (int d = 1; d < 256; d <<= 1) {      // Hillis-Steele inclusive scan
    unsigned v = (t >= d) ? s_scan[t - d] : 0u;
    __syncthreads();
    s_scan[t] += v;
    __syncthreads();
  }
  {
    unsigned excl = s_scan[t] - psum;      // exclusive offsets -> cursors
    s_hist[2 * t] = excl;
    s_hist[2 * t + 1] = excl + h0;
  }
  __syncthreads();
#pragma unroll
  for (int j = 0; j < 16; ++j) {
    const int i = t + j * 256;
    unsigned p = atomicAdd(&s_hist[mo[j]], 1u);
    unsigned tag = ((unsigned)((~i) & 0xFFF) << 12) | p;
    s_pts[p] = make_float4(tx[j], ty[j], tz[j], __uint_as_float(tag));
  }
  if (t == 0) idx_out[b * MS] = 0;
  __syncthreads();

  // ---- Phase B: own 16 sorted points + tight bbox ------------------------
  float px[16], py[16], pz[16], dist[16];
  unsigned lw[16];
#pragma unroll
  for (int j = 0; j < 16; ++j) {
    float4 p4 = s_pts[t * 16 + j];
    px[j] = p4.x; py[j] = p4.y; pz[j] = p4.z;
    lw[j] = __float_as_uint(p4.w);
    dist[j] = __builtin_inff();
  }
  float lox = px[0], hix = px[0], loy = py[0], hiy = py[0], loz = pz[0], hiz = pz[0];
#pragma unroll
  for (int j = 1; j < 16; ++j) {
    lox = fminf(lox, px[j]); hix = fmaxf(hix, px[j]);
    loy = fminf(loy, py[j]); hiy = fmaxf(hiy, py[j]);
    loz = fminf(loz, pz[j]); hiz = fmaxf(hiz, pz[j]);
  }
  // cached max key of this cell; bd=+inf forces first-iter dirty
  unsigned long long cache = ((unsigned long long)0x7F800000u << 32);

  const int w = t >> 6, lane = t & 63;
  float sx = s_first.x, sy = s_first.y, sz = s_first.z;

  for (int m = 1; m < MS; ++m) {
    const float bd = __uint_as_float((unsigned)(cache >> 32));
    float ddx = fmaxf(fmaxf(lox - sx, sx - hix), 0.f);
    float ddy = fmaxf(fmaxf(loy - sy, sy - hiy), 0.f);
    float ddz = fmaxf(fmaxf(loz - sz, sz - hiz), 0.f);
    float lb2 = (ddx * ddx + ddy * ddy) + ddz * ddz;
    if (lb2 * 0.9999988f < bd) {           // dirty: exact update + rebuild key
      unsigned long long nc = 0ull;
#pragma unroll
      for (int j = 0; j < 16; ++j) {
        float d2 = d2_exact(px[j], py[j], pz[j], sx, sy, sz);
        float nd = fminf(dist[j], d2);
        dist[j] = nd;
        unsigned long long ck =
            ((unsigned long long)__float_as_uint(nd) << 32) | lw[j];
        if (ck > nc) nc = ck;
      }
      cache = nc;
    }
    unsigned long long k = cache;
    k = dpp_max_step<0x111, 0xF>(k);  // row_shr:1
    k = dpp_max_step<0x112, 0xF>(k);  // row_shr:2
    k = dpp_max_step<0x114, 0xF>(k);  // row_shr:4
    k = dpp_max_step<0x118, 0xF>(k);  // row_shr:8
    k = dpp_max_step<0x142, 0xA>(k);  // row_bcast15
    k = dpp_max_step<0x143, 0xC>(k);  // row_bcast31 -> lane63 = wave max
    const int par = m & 1;
    if (lane == 63) s_red[par][w] = k;
    __syncthreads();
    ulonglong2 ab = *reinterpret_cast<const ulonglong2*>(&s_red[par][0]);
    ulonglong2 cd = *reinterpret_cast<const ulonglong2*>(&s_red[par][2]);
    unsigned long long kb = u64max(u64max(ab.x, ab.y), u64max(cd.x, cd.y));
    const unsigned kl = (unsigned)kb;
    if (t == 0) idx_out[b * MS + m] = 4095 - ((kl >> 12) & 0xFFF);
    float4 wp = s_pts[kl & 0xFFF];    // broadcast read of winner coords
    sx = wp.x; sy = wp.y; sz = wp.z;
  }
}

// ---- radius(top-64) + MFMA-bf16 MLP + masked neighbor max (R3, proven) ----
__global__ __launch_bounds__(512, 4) void radconv_kernel(
    const float* __restrict__ x, const float* __restrict__ pos,
    const int* __restrict__ idx,
    const float* __restrict__ W1, const float* __restrict__ B1,
    const float* __restrict__ W2, const float* __restrict__ B2,
    const float* __restrict__ W3, const float* __restrict__ B3,
    float* __restrict__ out) {
  const int t = threadIdx.x;
  const int g = blockIdx.x >> 9;          // graph
  const int qpair = blockIdx.x & 511;     // 512 blocks/graph * 2 queries
  const float* pb = pos + (size_t)g * NPER * 3;
  const float* xb = x + (size_t)g * NPER * CIN;

  __shared__ int s_cnt[2];
  __shared__ float s_ctr[2][4];
  __shared__ __align__(16) unsigned long long s_list[2][LCAP];  // 6 KB
  __shared__ int s_nbr[2][64];
  __shared__ __align__(16) unsigned short sFeat[2][64 * 104];   // 26 KB (reused as red)
  __shared__ __align__(16) unsigned short sW1[64 * 104];        // 13 KB  [col][k<=96pad]
  __shared__ __align__(16) unsigned short sW2[64 * 72];         // 9 KB   [col][k=64+pad]
  __shared__ __align__(16) unsigned short sW3[128 * 72];        // 18 KB

  if (t < 2) s_cnt[t] = 0;
  const int q0 = g * MS + qpair * 2;
  const int qiA = idx[q0], qiB = idx[q0 + 1];
  const float cAx = pb[qiA * 3], cAy = pb[qiA * 3 + 1], cAz = pb[qiA * 3 + 2];
  const float cBx = pb[qiB * 3], cBy = pb[qiB * 3 + 1], cBz = pb[qiB * 3 + 2];
  if (t == 0) { s_ctr[0][0] = cAx; s_ctr[0][1] = cAy; s_ctr[0][2] = cAz; }
  if (t == 1) { s_ctr[1][0] = cBx; s_ctr[1][1] = cBy; s_ctr[1][2] = cBz; }
  __syncthreads();  // B1: s_cnt zeroed

  // ---- search: 8 pts/thread, both queries --------------------------------
  {
    float pp[24];
    const float4* pv = (const float4*)(pb + (size_t)t * 24);
#pragma unroll
    for (int r = 0; r < 6; ++r) {
      float4 v = pv[r];
      pp[r * 4 + 0] = v.x; pp[r * 4 + 1] = v.y;
      pp[r * 4 + 2] = v.z; pp[r * 4 + 3] = v.w;
    }
#pragma unroll
    for (int jj = 0; jj < 8; ++jj) {
      const int j = t * 8 + jj;
      const float X = pp[jj * 3], Y = pp[jj * 3 + 1], Z = pp[jj * 3 + 2];
      float dA = d2_exact(X, Y, Z, cAx, cAy, cAz);
      if (dA <= 0.04f) {  // f32(0.04) == JAX's R*R
        int p = atomicAdd(&s_cnt[0], 1);
        if (p < LCAP)
          s_list[0][p] = ((unsigned long long)__float_as_uint(dA) << 32) | (unsigned)j;
      }
      float dB = d2_exact(X, Y, Z, cBx, cBy, cBz);
      if (dB <= 0.04f) {
        int p = atomicAdd(&s_cnt[1], 1);
        if (p < LCAP)
          s_list[1][p] = ((unsigned long long)__float_as_uint(dB) << 32) | (unsigned)j;
      }
    }
  }
  // ---- stage weights (bf16, transposed) — independent of search ----------
  for (int ee = t; ee < 64 * 64; ee += 512) {           // zero W1 k-pad 67..103
    int c = ee >> 6, kk = 67 + (ee & 63);
    if (kk < 104) sW1[c * 104 + kk] = 0;
  }
  for (int e = t; e < 67 * 64; e += 512) {              // W1t[c][k] = W1[k][c]
    int k = e >> 6, c = e & 63;
    sW1[c * 104 + k] = f2bf(W1[e]);
  }
  for (int e = t; e < 64 * 64; e += 512) {
    int k = e >> 6, c = e & 63;
    sW2[c * 72 + k] = f2bf(W2[e]);
  }
  for (int e = t; e < 64 * 128; e += 512) {
    int k = e >> 7, c = e & 127;
    sW3[c * 72 + k] = f2bf(W3[e]);
  }
  __syncthreads();  // B2: lists + weights ready

  const int w = t >> 6, lane = t & 63;
  const int c0 = min(min(s_cnt[0], LCAP), 64);
  const int c1 = min(min(s_cnt[1], LCAP), 64);

  // ---- exact top-64 by (d2, idx) via rank; 4 waves per query -------------
  {
    const int rq = w >> 2;
    const int nsurv = min(s_cnt[rq], LCAP);
    for (int e = (w & 3) * 64 + lane; e < nsurv; e += 256) {
      unsigned long long mykey = s_list[rq][e];
      int rank = 0;
      int o = 0;
      for (; o + 8 <= nsurv; o += 8) {
        unsigned long long k0 = s_list[rq][o + 0], k1 = s_list[rq][o + 1];
        unsigned long long k2 = s_list[rq][o + 2], k3 = s_list[rq][o + 3];
        unsigned long long k4 = s_list[rq][o + 4], k5 = s_list[rq][o + 5];
        unsigned long long k6 = s_list[rq][o + 6], k7 = s_list[rq][o + 7];
        rank += (k0 < mykey) + (k1 < mykey) + (k2 < mykey) + (k3 < mykey) +
                (k4 < mykey) + (k5 < mykey) + (k6 < mykey) + (k7 < mykey);
      }
      for (; o < nsurv; ++o) rank += (s_list[rq][o] < mykey) ? 1 : 0;
      if (rank < 64) s_nbr[rq][rank] = (int)(mykey & 0xFFFFFFFFull);
    }
  }
  __syncthreads();  // B3: nbr lists ready

  // ---- gather feat rows: [x_j bf16 (64) | rel (3) | 0 pad ... 96) --------
  {
    const int slot = t >> 2, part = t & 3;   // 128 slots x 4 parts
    const int gq = slot >> 6, s = slot & 63;
    const int cq = gq ? c1 : c0;
    unsigned short* frow = &sFeat[gq][s * 104];
    uint4 z; z.x = z.y = z.z = z.w = 0u;
    if (s < cq) {
      const int j = s_nbr[gq][s];
      const float4* xr = (const float4*)(xb + (size_t)j * CIN + part * 16);
      float4 v0 = xr[0], v1 = xr[1], v2 = xr[2], v3 = xr[3];
      uint4 w0, w1;
      w0.x = f2bf(v0.x) | ((unsigned)f2bf(v0.y) << 16);
      w0.y = f2bf(v0.z) | ((unsigned)f2bf(v0.w) << 16);
      w0.z = f2bf(v1.x) | ((unsigned)f2bf(v1.y) << 16);
      w0.w = f2bf(v1.z) | ((unsigned)f2bf(v1.w) << 16);
      w1.x = f2bf(v2.x) | ((unsigned)f2bf(v2.y) << 16);
      w1.y = f2bf(v2.z) | ((unsigned)f2bf(v2.w) << 16);
      w1.z = f2bf(v3.x) | ((unsigned)f2bf(v3.y) << 16);
      w1.w = f2bf(v3.z) | ((unsigned)f2bf(v3.w) << 16);
      *(uint4*)(frow + part * 16) = w0;
      *(uint4*)(frow + part * 16 + 8) = w1;
      uint4 rz = z;
      if (part == 0) {
        const float cx = gq ? cBx : cAx, cy = gq ? cBy : cAy, cz = gq ? cBz : cAz;
        rz.x = f2bf(pb[j * 3] - cx) | ((unsigned)f2bf(pb[j * 3 + 1] - cy) << 16);
        rz.y = (unsigned)f2bf(pb[j * 3 + 2] - cz);
      }
      *(uint4*)(frow + 64 + part * 8) = rz;
    } else {
      *(uint4*)(frow + part * 16) = z;
      *(uint4*)(frow + part * 16 + 8) = z;
      *(uint4*)(frow + 64 + part * 8) = z;
    }
  }
  __syncthreads();  // B4: feat ready

  // ---- MFMA MLP: wave -> (query qq2, row tile mt) ------------------------
  const int qq2 = w >> 2;
  const int mt = w & 3;
  const int lo = lane & 15, hi = lane >> 4;
  unsigned short* F = &sFeat[qq2][0];
  const int arow = (16 * mt + lo) * 104;
  const int hrow = (16 * mt + hi * 4) * 104;

  // layer 1: K=96 (3 steps), N=64 (4 tiles)
  {
    f32x4 acc[4];
#pragma unroll
    for (int n = 0; n < 4; ++n) {
      float bb = B1[n * 16 + lo];
      acc[n] = (f32x4){bb, bb, bb, bb};
    }
    s16x8 a0 = *(const s16x8*)(F + arow + 0 + hi * 8);
    s16x8 a1 = *(const s16x8*)(F + arow + 32 + hi * 8);
    s16x8 a2 = *(const s16x8*)(F + arow + 64 + hi * 8);
#pragma unroll
    for (int n = 0; n < 4; ++n) {
      const unsigned short* Bp = &sW1[(n * 16 + lo) * 104 + hi * 8];
      s16x8 b0 = *(const s16x8*)(Bp);
      s16x8 b1 = *(const s16x8*)(Bp + 32);
      s16x8 b2 = *(const s16x8*)(Bp + 64);
      acc[n] = __builtin_amdgcn_mfma_f32_16x16x32_bf16(a0, b0, acc[n], 0, 0, 0);
      acc[n] = __builtin_amdgcn_mfma_f32_16x16x32_bf16(a1, b1, acc[n], 0, 0, 0);
      acc[n] = __builtin_amdgcn_mfma_f32_16x16x32_bf16(a2, b2, acc[n], 0, 0, 0);
    }
#pragma unroll
    for (int n = 0; n < 4; ++n)
#pragma unroll
      for (int r = 0; r < 4; ++r)
        F[hrow + r * 104 + n * 16 + lo] = f2bf(fmaxf(acc[n][r], 0.f));
  }
  // layer 2: K=64 (2 steps), N=64
  {
    f32x4 acc[4];
#pragma unroll
    for (int n = 0; n < 4; ++n) {
      float bb = B2[n * 16 + lo];
      acc[n] = (f32x4){bb, bb, bb, bb};
    }
    s16x8 a0 = *(const s16x8*)(F + arow + 0 + hi * 8);
    s16x8 a1 = *(const s16x8*)(F + arow + 32 + hi * 8);
#pragma unroll
    for (int n = 0; n < 4; ++n) {
      const unsigned short* Bp = &sW2[(n * 16 + lo) * 72 + hi * 8];
      s16x8 b0 = *(const s16x8*)(Bp);
      s16x8 b1 = *(const s16x8*)(Bp + 32);
      acc[n] = __builtin_amdgcn_mfma_f32_16x16x32_bf16(a0, b0, acc[n], 0, 0, 0);
      acc[n] = __builtin_amdgcn_mfma_f32_16x16x32_bf16(a1, b1, acc[n], 0, 0, 0);
    }
#pragma unroll
    for (int n = 0; n < 4; ++n)
#pragma unroll
      for (int r = 0; r < 4; ++r)
        F[hrow + r * 104 + n * 16 + lo] = f2bf(fmaxf(acc[n][r], 0.f));
  }
  // layer 3: K=64 (2 steps), N=128 (8 tiles), fused masked row-max
  float pm[8];
  {
    const int cq = qq2 ? c1 : c0;
    f32x4 acc[8];
#pragma unroll
    for (int n = 0; n < 8; ++n) {
      float bb = B3[n * 16 + lo];
      acc[n] = (f32x4){bb, bb, bb, bb};
    }
    s16x8 a0 = *(const s16x8*)(F + arow + 0 + hi * 8);
    s16x8 a1 = *(const s16x8*)(F + arow + 32 + hi * 8);
#pragma unroll
    for (int n = 0; n < 8; ++n) {
      const unsigned short* Bp = &sW3[(n * 16 + lo) * 72 + hi * 8];
      s16x8 b0 = *(const s16x8*)(Bp);
      s16x8 b1 = *(const s16x8*)(Bp + 32);
      acc[n] = __builtin_amdgcn_mfma_f32_16x16x32_bf16(a0, b0, acc[n], 0, 0, 0);
      acc[n] = __builtin_amdgcn_mfma_f32_16x16x32_bf16(a1, b1, acc[n], 0, 0, 0);
    }
#pragma unroll
    for (int n = 0; n < 8; ++n) {
      float v = -1e30f;
#pragma unroll
      for (int r = 0; r < 4; ++r) {
        int row = 16 * mt + hi * 4 + r;
        if (row < cq) v = fmaxf(v, fmaxf(acc[n][r], 0.f));
      }
      pm[n] = v;
    }
  }
  __syncthreads();  // B5: all sFeat reads done -> reuse as reduction buffer

  float* red = (float*)&sFeat[0][0];  // [2][128][17] floats = 17.4 KB
#pragma unroll
  for (int n = 0; n < 8; ++n)
    red[((qq2 * 128) + n * 16 + lo) * 17 + mt * 4 + hi] = pm[n];
  __syncthreads();  // B6

  if (t < 256) {
    const int gq = t >> 7, cc = t & 127;
    const float* rp = red + (gq * 128 + cc) * 17;
    float v = rp[0];
#pragma unroll
    for (int p = 1; p < 16; ++p) v = fmaxf(v, rp[p]);
    const int qrow = q0 + gq;
    out[(size_t)qrow * 128 + cc] = v;
  }
  if (t == 256 || t == 257) {
    const int gq = t - 256;
    const int qrow = q0 + gq;
    out[524288 + qrow * 3 + 0] = s_ctr[gq][0];
    out[524288 + qrow * 3 + 1] = s_ctr[gq][1];
    out[524288 + qrow * 3 + 2] = s_ctr[gq][2];
    out[536576 + qrow] = (float)g;
  }
}

extern "C" void kernel_launch(void* const* d_in, const int* in_sizes, int n_in,
                              void* d_out, int out_size, void* d_ws, size_t ws_size,
                              hipStream_t stream) {
  const float* x   = (const float*)d_in[0];
  const float* pos = (const float*)d_in[1];
  const float* W1  = (const float*)d_in[3];
  const float* B1  = (const float*)d_in[4];
  const float* W2  = (const float*)d_in[5];
  const float* B2  = (const float*)d_in[6];
  const float* W3  = (const float*)d_in[7];
  const float* B3  = (const float*)d_in[8];
  float* out = (float*)d_out;
  int* idx = (int*)d_ws;  // 4096 ints

  fps_kernel<<<4, 256, 0, stream>>>(pos, idx);
  radconv_kernel<<<2048, 512, 0, stream>>>(x, pos, idx, W1, B1, W2, B2, W3, B3, out);
}

// Round 5
// 773.076 us; speedup vs baseline: 1.0304x; 1.0304x over previous
//
#include <hip/hip_runtime.h>

#define NPER 4096
#define MS   1024
#define CIN  64
#define LCAP 384
#define SMB  74288

typedef float  f32x4 __attribute__((ext_vector_type(4)));
typedef float  f32x2 __attribute__((ext_vector_type(2)));
typedef short  s16x8 __attribute__((ext_vector_type(8)));

// Packed fp32 (CDNA dual-pump). Per-component IEEE ops -> rounding identical
// to scalar, so FPS decisions stay bit-exact vs the reference.
__device__ __forceinline__ f32x2 pk_add(f32x2 a, f32x2 b) {
  f32x2 d;
  asm("v_pk_add_f32 %0, %1, %2" : "=v"(d) : "v"(a), "v"(b));
  return d;
}
__device__ __forceinline__ f32x2 pk_mul(f32x2 a, f32x2 b) {
  f32x2 d;
  asm("v_pk_mul_f32 %0, %1, %2" : "=v"(d) : "v"(a), "v"(b));
  return d;
}

// Exact d2 matching XLA: sub, rounded squares, left-assoc sum; no fma.
__device__ __forceinline__ float d2_exact(float ax, float ay, float az,
                                          float bx, float by, float bz) {
  float dx = __fsub_rn(ax, bx);
  float dy = __fsub_rn(ay, by);
  float dz = __fsub_rn(az, bz);
  return __fadd_rn(__fadd_rn(__fmul_rn(dx, dx), __fmul_rn(dy, dy)), __fmul_rn(dz, dz));
}

__device__ __forceinline__ unsigned short f2bf(float f) {
  unsigned b = __float_as_uint(f);
  return (unsigned short)((b + 0x7FFFu + ((b >> 16) & 1u)) >> 16);
}

template <int CTRL, int RMASK>
__device__ __forceinline__ unsigned long long dpp_max_step(unsigned long long k) {
  int hi = (int)(unsigned)(k >> 32);
  int lo = (int)(unsigned)(k & 0xFFFFFFFFull);
  int thi = __builtin_amdgcn_update_dpp(hi, hi, CTRL, RMASK, 0xF, false);
  int tlo = __builtin_amdgcn_update_dpp(lo, lo, CTRL, RMASK, 0xF, false);
  unsigned long long t =
      ((unsigned long long)(unsigned)thi << 32) | (unsigned)tlo;
  return t > k ? t : k;
}

__device__ __forceinline__ unsigned long long u64max(unsigned long long a,
                                                    unsigned long long b) {
  return a > b ? a : b;
}

// Fused kernel. Roles by arrival ticket (deadlock-free under any dispatch
// order): first 4 arrivals run FPS (one graph each, R2-proven structure,
// pk-f32 compute, 256 active threads of 512); the rest are radconv consumers
// (2 queries each) that spin on prog[g] published by FPS every 32 samples.
__global__ __launch_bounds__(512, 4) void fused_kernel(
    const float* __restrict__ x, const float* __restrict__ pos,
    const float* __restrict__ W1, const float* __restrict__ B1,
    const float* __restrict__ W2, const float* __restrict__ B2,
    const float* __restrict__ W3, const float* __restrict__ B3,
    float* __restrict__ out, int* __restrict__ idxp, int* __restrict__ ctrl) {
  const int t = threadIdx.x;
  __shared__ __align__(16) char smraw[SMB];
  __shared__ int s_role;

  if (t == 0) s_role = atomicAdd(&ctrl[0], 1);
  __syncthreads();
  const int role = s_role;
  const int w = t >> 6, lane = t & 63;

  if (role < 4) {
    // ==================== FPS (graph b = role) ============================
    __builtin_amdgcn_s_setprio(3);  // protect the latency chain from
                                    // co-resident consumer waves
    const int b = role;
    float4* s_pos4 = (float4*)smraw;                              // 64 KB
    unsigned long long* s_red = (unsigned long long*)(smraw + 65536);
    const float* pb = pos + (size_t)b * NPER * 3;
    for (int i = t; i < NPER; i += 512)
      s_pos4[i] = make_float4(pb[i * 3], pb[i * 3 + 1], pb[i * 3 + 2], 0.f);
    if (t == 0) idxp[b * MS] = 0;
    __syncthreads();

    f32x2 npx[8], npy[8], npz[8], dist2[8];
    if (t < 256) {
#pragma unroll
      for (int p = 0; p < 8; ++p) {
        float4 a = s_pos4[t + (2 * p) * 256];
        float4 c = s_pos4[t + (2 * p + 1) * 256];
        npx[p] = (f32x2){-a.x, -c.x};
        npy[p] = (f32x2){-a.y, -c.y};
        npz[p] = (f32x2){-a.z, -c.z};
        dist2[p] = (f32x2){__builtin_inff(), __builtin_inff()};
      }
    }
    float sx = s_pos4[0].x, sy = s_pos4[0].y, sz = s_pos4[0].z;

    for (int m = 1; m < MS; ++m) {
      const int par = m & 1;
      if (t < 256) {
        float bd = -1.0f;
        int bi = 0;
        f32x2 sxx = (f32x2){sx, sx}, syy = (f32x2){sy, sy}, szz = (f32x2){sz, sz};
#pragma unroll
        for (int p = 0; p < 8; ++p) {
          f32x2 dx = pk_add(sxx, npx[p]);      // sx - x (negation exact)
          f32x2 dy = pk_add(syy, npy[p]);
          f32x2 dz = pk_add(szz, npz[p]);
          f32x2 d2 = pk_add(pk_add(pk_mul(dx, dx), pk_mul(dy, dy)), pk_mul(dz, dz));
          float n0 = fminf(dist2[p][0], d2[0]);
          float n1 = fminf(dist2[p][1], d2[1]);
          dist2[p][0] = n0;
          dist2[p][1] = n1;
          if (n0 > bd) { bd = n0; bi = t + (2 * p) * 256; }      // strict >:
          if (n1 > bd) { bd = n1; bi = t + (2 * p + 1) * 256; }  // lowest idx tie
        }
        unsigned long long k =
            ((unsigned long long)__float_as_uint(bd) << 32) | (unsigned)(~bi);
        k = dpp_max_step<0x111, 0xF>(k);  // row_shr:1
        k = dpp_max_step<0x112, 0xF>(k);  // row_shr:2
        k = dpp_max_step<0x114, 0xF>(k);  // row_shr:4
        k = dpp_max_step<0x118, 0xF>(k);  // row_shr:8
        k = dpp_max_step<0x142, 0xA>(k);  // row_bcast15
        k = dpp_max_step<0x143, 0xC>(k);  // row_bcast31 -> lane63 = wave max
        if (lane == 63) s_red[par * 4 + w] = k;
      }
      __syncthreads();
      if (t < 256) {
        ulonglong2 ab = *reinterpret_cast<const ulonglong2*>(&s_red[par * 4 + 0]);
        ulonglong2 cd = *reinterpret_cast<const ulonglong2*>(&s_red[par * 4 + 2]);
        unsigned long long kb = u64max(u64max(ab.x, ab.y), u64max(cd.x, cd.y));
        const int nx = (int)(~(unsigned)(kb & 0xFFFFFFFFull));
        if (t == 0) {
          idxp[b * MS + m] = nx;
          if ((m & 31) == 31) {            // publish 32 samples (release)
            __threadfence();
            atomicExch(&ctrl[1 + b], m + 1);
          }
        }
        float4 wp = s_pos4[nx];            // broadcast read
        sx = wp.x; sy = wp.y; sz = wp.z;
      }
    }
    return;
  }

  // ==================== radconv consumer (2 queries) ======================
  const int pp = role - 4;          // 0..2047
  const int g = pp >> 9;            // graph
  const int qpair = pp & 511;
  const float* pb = pos + (size_t)g * NPER * 3;
  const float* xb = x + (size_t)g * NPER * CIN;

  unsigned short* sFeat = (unsigned short*)smraw;                 // 2*6656
  unsigned short* sW1 = (unsigned short*)(smraw + 26624);         // [c][104]
  unsigned short* sW2 = (unsigned short*)(smraw + 39936);         // [c][72]
  unsigned short* sW3 = (unsigned short*)(smraw + 49152);         // [c][72]
  unsigned long long* s_list = (unsigned long long*)(smraw + 67584);  // 2*LCAP
  int* s_nbr = (int*)(smraw + 73728);                             // 2*64
  int* s_cnt = (int*)(smraw + 74240);
  float* s_ctr = (float*)(smraw + 74248);                         // 2*4
  int* s_qi = (int*)(smraw + 74280);

  const int q0 = g * MS + qpair * 2;
  if (t == 0) {
    const int need = qpair * 2 + 2;
    while (atomicAdd(&ctrl[1 + g], 0) < need) __builtin_amdgcn_s_sleep(32);
    s_qi[0] = atomicAdd(&idxp[q0], 0);       // coherence-point reads
    s_qi[1] = atomicAdd(&idxp[q0 + 1], 0);
  }
  if (t < 2) s_cnt[t] = 0;
  __syncthreads();  // B1: idx ready, s_cnt zeroed

  const int qiA = s_qi[0], qiB = s_qi[1];
  const float cAx = pb[qiA * 3], cAy = pb[qiA * 3 + 1], cAz = pb[qiA * 3 + 2];
  const float cBx = pb[qiB * 3], cBy = pb[qiB * 3 + 1], cBz = pb[qiB * 3 + 2];
  if (t == 0) { s_ctr[0] = cAx; s_ctr[1] = cAy; s_ctr[2] = cAz; }
  if (t == 1) { s_ctr[4] = cBx; s_ctr[5] = cBy; s_ctr[6] = cBz; }

  // ---- search: 8 pts/thread, both queries --------------------------------
  {
    float ppt[24];
    const float4* pv = (const float4*)(pb + (size_t)t * 24);
#pragma unroll
    for (int r = 0; r < 6; ++r) {
      float4 v = pv[r];
      ppt[r * 4 + 0] = v.x; ppt[r * 4 + 1] = v.y;
      ppt[r * 4 + 2] = v.z; ppt[r * 4 + 3] = v.w;
    }
#pragma unroll
    for (int jj = 0; jj < 8; ++jj) {
      const int j = t * 8 + jj;
      const float X = ppt[jj * 3], Y = ppt[jj * 3 + 1], Z = ppt[jj * 3 + 2];
      float dA = d2_exact(X, Y, Z, cAx, cAy, cAz);
      if (dA <= 0.04f) {  // f32(0.04) == JAX's R*R
        int p = atomicAdd(&s_cnt[0], 1);
        if (p < LCAP)
          s_list[p] = ((unsigned long long)__float_as_uint(dA) << 32) | (unsigned)j;
      }
      float dB = d2_exact(X, Y, Z, cBx, cBy, cBz);
      if (dB <= 0.04f) {
        int p = atomicAdd(&s_cnt[1], 1);
        if (p < LCAP)
          s_list[LCAP + p] =
              ((unsigned long long)__float_as_uint(dB) << 32) | (unsigned)j;
      }
    }
  }
  // ---- stage weights (bf16, transposed) ----------------------------------
  for (int ee = t; ee < 64 * 64; ee += 512) {
    int c = ee >> 6, kk = 67 + (ee & 63);
    if (kk < 104) sW1[c * 104 + kk] = 0;
  }
  for (int e = t; e < 67 * 64; e += 512) {
    int k = e >> 6, c = e & 63;
    sW1[c * 104 + k] = f2bf(W1[e]);
  }
  for (int e = t; e < 64 * 64; e += 512) {
    int k = e >> 6, c = e & 63;
    sW2[c * 72 + k] = f2bf(W2[e]);
  }
  for (int e = t; e < 64 * 128; e += 512) {
    int k = e >> 7, c = e & 127;
    sW3[c * 72 + k] = f2bf(W3[e]);
  }
  __syncthreads();  // B2: lists + weights ready

  const int c0 = min(min(s_cnt[0], LCAP), 64);
  const int c1 = min(min(s_cnt[1], LCAP), 64);

  // ---- exact top-64 by (d2, idx) via rank; 4 waves per query -------------
  {
    const int rq = w >> 2;
    const unsigned long long* L = s_list + rq * LCAP;
    const int nsurv = min(s_cnt[rq], LCAP);
    for (int e = (w & 3) * 64 + lane; e < nsurv; e += 256) {
      unsigned long long mykey = L[e];
      int rank = 0;
      int o = 0;
      for (; o + 8 <= nsurv; o += 8) {
        unsigned long long k0 = L[o + 0], k1 = L[o + 1];
        unsigned long long k2 = L[o + 2], k3 = L[o + 3];
        unsigned long long k4 = L[o + 4], k5 = L[o + 5];
        unsigned long long k6 = L[o + 6], k7 = L[o + 7];
        rank += (k0 < mykey) + (k1 < mykey) + (k2 < mykey) + (k3 < mykey) +
                (k4 < mykey) + (k5 < mykey) + (k6 < mykey) + (k7 < mykey);
      }
      for (; o < nsurv; ++o) rank += (L[o] < mykey) ? 1 : 0;
      if (rank < 64) s_nbr[rq * 64 + rank] = (int)(mykey & 0xFFFFFFFFull);
    }
  }
  __syncthreads();  // B3: nbr lists ready

  // ---- gather feat rows: [x_j bf16 (64) | rel (3) | 0 pad ... 96) --------
  {
    const int slot = t >> 2, part = t & 3;
    const int gq = slot >> 6, s = slot & 63;
    const int cq = gq ? c1 : c0;
    unsigned short* frow = sFeat + gq * 6656 + s * 104;
    uint4 z; z.x = z.y = z.z = z.w = 0u;
    if (s < cq) {
      const int j = s_nbr[gq * 64 + s];
      const float4* xr = (const float4*)(xb + (size_t)j * CIN + part * 16);
      float4 v0 = xr[0], v1 = xr[1], v2 = xr[2], v3 = xr[3];
      uint4 w0, w1;
      w0.x = f2bf(v0.x) | ((unsigned)f2bf(v0.y) << 16);
      w0.y = f2bf(v0.z) | ((unsigned)f2bf(v0.w) << 16);
      w0.z = f2bf(v1.x) | ((unsigned)f2bf(v1.y) << 16);
      w0.w = f2bf(v1.z) | ((unsigned)f2bf(v1.w) << 16);
      w1.x = f2bf(v2.x) | ((unsigned)f2bf(v2.y) << 16);
      w1.y = f2bf(v2.z) | ((unsigned)f2bf(v2.w) << 16);
      w1.z = f2bf(v3.x) | ((unsigned)f2bf(v3.y) << 16);
      w1.w = f2bf(v3.z) | ((unsigned)f2bf(v3.w) << 16);
      *(uint4*)(frow + part * 16) = w0;
      *(uint4*)(frow + part * 16 + 8) = w1;
      uint4 rz = z;
      if (part == 0) {
        const float cx = gq ? cBx : cAx, cy = gq ? cBy : cAy, cz = gq ? cBz : cAz;
        rz.x = f2bf(pb[j * 3] - cx) | ((unsigned)f2bf(pb[j * 3 + 1] - cy) << 16);
        rz.y = (unsigned)f2bf(pb[j * 3 + 2] - cz);
      }
      *(uint4*)(frow + 64 + part * 8) = rz;
    } else {
      *(uint4*)(frow + part * 16) = z;
      *(uint4*)(frow + part * 16 + 8) = z;
      *(uint4*)(frow + 64 + part * 8) = z;
    }
  }
  __syncthreads();  // B4: feat ready

  // ---- MFMA MLP: wave -> (query qq2, row tile mt) ------------------------
  const int qq2 = w >> 2;
  const int mt = w & 3;
  const int lo = lane & 15, hi = lane >> 4;
  unsigned short* F = sFeat + qq2 * 6656;
  const int arow = (16 * mt + lo) * 104;
  const int hrow = (16 * mt + hi * 4) * 104;

  {  // layer 1: K=96 (3 steps), N=64
    f32x4 acc[4];
#pragma unroll
    for (int n = 0; n < 4; ++n) {
      float bb = B1[n * 16 + lo];
      acc[n] = (f32x4){bb, bb, bb, bb};
    }
    s16x8 a0 = *(const s16x8*)(F + arow + 0 + hi * 8);
    s16x8 a1 = *(const s16x8*)(F + arow + 32 + hi * 8);
    s16x8 a2 = *(const s16x8*)(F + arow + 64 + hi * 8);
#pragma unroll
    for (int n = 0; n < 4; ++n) {
      const unsigned short* Bp = &sW1[(n * 16 + lo) * 104 + hi * 8];
      s16x8 b0 = *(const s16x8*)(Bp);
      s16x8 b1 = *(const s16x8*)(Bp + 32);
      s16x8 b2 = *(const s16x8*)(Bp + 64);
      acc[n] = __builtin_amdgcn_mfma_f32_16x16x32_bf16(a0, b0, acc[n], 0, 0, 0);
      acc[n] = __builtin_amdgcn_mfma_f32_16x16x32_bf16(a1, b1, acc[n], 0, 0, 0);
      acc[n] = __builtin_amdgcn_mfma_f32_16x16x32_bf16(a2, b2, acc[n], 0, 0, 0);
    }
#pragma unroll
    for (int n = 0; n < 4; ++n)
#pragma unroll
      for (int r = 0; r < 4; ++r)
        F[hrow + r * 104 + n * 16 + lo] = f2bf(fmaxf(acc[n][r], 0.f));
  }
  {  // layer 2: K=64 (2 steps), N=64
    f32x4 acc[4];
#pragma unroll
    for (int n = 0; n < 4; ++n) {
      float bb = B2[n * 16 + lo];
      acc[n] = (f32x4){bb, bb, bb, bb};
    }
    s16x8 a0 = *(const s16x8*)(F + arow + 0 + hi * 8);
    s16x8 a1 = *(const s16x8*)(F + arow + 32 + hi * 8);
#pragma unroll
    for (int n = 0; n < 4; ++n) {
      const unsigned short* Bp = &sW2[(n * 16 + lo) * 72 + hi * 8];
      s16x8 b0 = *(const s16x8*)(Bp);
      s16x8 b1 = *(const s16x8*)(Bp + 32);
      acc[n] = __builtin_amdgcn_mfma_f32_16x16x32_bf16(a0, b0, acc[n], 0, 0, 0);
      acc[n] = __builtin_amdgcn_mfma_f32_16x16x32_bf16(a1, b1, acc[n], 0, 0, 0);
    }
#pragma unroll
    for (int n = 0; n < 4; ++n)
#pragma unroll
      for (int r = 0; r < 4; ++r)
        F[hrow + r * 104 + n * 16 + lo] = f2bf(fmaxf(acc[n][r], 0.f));
  }
  float pm[8];
  {  // layer 3: K=64 (2 steps), N=128, fused masked row-max
    const int cq = qq2 ? c1 : c0;
    f32x4 acc[8];
#pragma unroll
    for (int n = 0; n < 8; ++n) {
      float bb = B3[n * 16 + lo];
      acc[n] = (f32x4){bb, bb, bb, bb};
    }
    s16x8 a0 = *(const s16x8*)(F + arow + 0 + hi * 8);
    s16x8 a1 = *(const s16x8*)(F + arow + 32 + hi * 8);
#pragma unroll
    for (int n = 0; n < 8; ++n) {
      const unsigned short* Bp = &sW3[(n * 16 + lo) * 72 + hi * 8];
      s16x8 b0 = *(const s16x8*)(Bp);
      s16x8 b1 = *(const s16x8*)(Bp + 32);
      acc[n] = __builtin_amdgcn_mfma_f32_16x16x32_bf16(a0, b0, acc[n], 0, 0, 0);
      acc[n] = __builtin_amdgcn_mfma_f32_16x16x32_bf16(a1, b1, acc[n], 0, 0, 0);
    }
#pragma unroll
    for (int n = 0; n < 8; ++n) {
      float v = -1e30f;
#pragma unroll
      for (int r = 0; r < 4; ++r) {
        int row = 16 * mt + hi * 4 + r;
        if (row < cq) v = fmaxf(v, fmaxf(acc[n][r], 0.f));
      }
      pm[n] = v;
    }
  }
  __syncthreads();  // B5: sFeat reads done -> reuse as reduction buffer

  float* red = (float*)sFeat;  // [2][128][17] floats
#pragma unroll
  for (int n = 0; n < 8; ++n)
    red[((qq2 * 128) + n * 16 + lo) * 17 + mt * 4 + hi] = pm[n];
  __syncthreads();  // B6

  if (t < 256) {
    const int gq = t >> 7, cc = t & 127;
    const float* rp = red + (gq * 128 + cc) * 17;
    float v = rp[0];
#pragma unroll
    for (int p = 1; p < 16; ++p) v = fmaxf(v, rp[p]);
    out[(size_t)(q0 + gq) * 128 + cc] = v;
  }
  if (t == 256 || t == 257) {
    const int gq = t - 256;
    const int qrow = q0 + gq;
    out[524288 + qrow * 3 + 0] = s_ctr[gq * 4 + 0];
    out[524288 + qrow * 3 + 1] = s_ctr[gq * 4 + 1];
    out[524288 + qrow * 3 + 2] = s_ctr[gq * 4 + 2];
    out[536576 + qrow] = (float)g;
  }
}

extern "C" void kernel_launch(void* const* d_in, const int* in_sizes, int n_in,
                              void* d_out, int out_size, void* d_ws, size_t ws_size,
                              hipStream_t stream) {
  const float* x   = (const float*)d_in[0];
  const float* pos = (const float*)d_in[1];
  const float* W1  = (const float*)d_in[3];
  const float* B1  = (const float*)d_in[4];
  const float* W2  = (const float*)d_in[5];
  const float* B2  = (const float*)d_in[6];
  const float* W3  = (const float*)d_in[7];
  const float* B3  = (const float*)d_in[8];
  float* out = (float*)d_out;
  int* idx = (int*)d_ws;          // [4096] sample indices
  int* ctrl = idx + 4096;         // [0]=ticket, [1..4]=prog per graph

  hipMemsetAsync(ctrl, 0, 20, stream);  // reset ticket+progress each call
  fused_kernel<<<2052, 512, 0, stream>>>(x, pos, W1, B1, W2, B2, W3, B3,
                                         out, idx, ctrl);
}

// Round 7
// 695.616 us; speedup vs baseline: 1.1452x; 1.1114x over previous
//
#include <hip/hip_runtime.h>

#define NPER 4096
#define MS   1024
#define CIN  64
#define LCAP 384

typedef float  f32x4 __attribute__((ext_vector_type(4)));
typedef float  f32x2 __attribute__((ext_vector_type(2)));
typedef short  s16x8 __attribute__((ext_vector_type(8)));

// Packed fp32 (CDNA dual-pump). Per-component IEEE rounding identical to
// scalar ops; negation is exact, so sx + (-x) == sx - x bit-for-bit.
// PROVEN exact by R5 (absmax unchanged vs scalar R3/R4).
__device__ __forceinline__ f32x2 pk_add(f32x2 a, f32x2 b) {
  f32x2 d;
  asm("v_pk_add_f32 %0, %1, %2" : "=v"(d) : "v"(a), "v"(b));
  return d;
}
__device__ __forceinline__ f32x2 pk_mul(f32x2 a, f32x2 b) {
  f32x2 d;
  asm("v_pk_mul_f32 %0, %1, %2" : "=v"(d) : "v"(a), "v"(b));
  return d;
}

// Exact d2 matching XLA: sub, rounded squares, left-assoc sum; no fma.
__device__ __forceinline__ float d2_exact(float ax, float ay, float az,
                                          float bx, float by, float bz) {
  float dx = __fsub_rn(ax, bx);
  float dy = __fsub_rn(ay, by);
  float dz = __fsub_rn(az, bz);
  return __fadd_rn(__fadd_rn(__fmul_rn(dx, dx), __fmul_rn(dy, dy)), __fmul_rn(dz, dz));
}

__device__ __forceinline__ unsigned short f2bf(float f) {
  unsigned b = __float_as_uint(f);
  return (unsigned short)((b + 0x7FFFu + ((b >> 16) & 1u)) >> 16);
}

template <int CTRL, int RMASK>
__device__ __forceinline__ unsigned long long dpp_max_step(unsigned long long k) {
  int hi = (int)(unsigned)(k >> 32);
  int lo = (int)(unsigned)(k & 0xFFFFFFFFull);
  int thi = __builtin_amdgcn_update_dpp(hi, hi, CTRL, RMASK, 0xF, false);
  int tlo = __builtin_amdgcn_update_dpp(lo, lo, CTRL, RMASK, 0xF, false);
  unsigned long long t =
      ((unsigned long long)(unsigned)thi << 32) | (unsigned)tlo;
  return t > k ? t : k;
}

__device__ __forceinline__ unsigned long long u64max(unsigned long long a,
                                                    unsigned long long b) {
  return a > b ? a : b;
}

// ---------------- FPS: one block per graph, 256 threads ---------------------
// R2-proven reduce structure (597 us) + R5-proven pk-f32 compute.
// Per iter: pk d2 for 8 pairs + scalar min/argmax -> DPP butterfly (lane63 =
// wave max) -> lane63 writes key -> ONE barrier -> all threads reduce the 4
// wave keys via 2 b128 broadcast reads + tree -> winner coords via one b128.
// s_red parity-double-buffered (no second barrier needed).
__global__ __launch_bounds__(256) void fps_kernel(const float* __restrict__ pos,
                                                  int* __restrict__ idx_out) {
  const int b = blockIdx.x;
  const int t = threadIdx.x;
  __shared__ float4 s_pos4[NPER];                       // 64 KB
  __shared__ __align__(16) unsigned long long s_red[2][4];
  const float* pb = pos + (size_t)b * NPER * 3;
  for (int i = t; i < NPER; i += 256)
    s_pos4[i] = make_float4(pb[i * 3], pb[i * 3 + 1], pb[i * 3 + 2], 0.f);
  if (t == 0) idx_out[b * MS] = 0;
  __syncthreads();

  f32x2 npx[8], npy[8], npz[8], dist2[8];
#pragma unroll
  for (int p = 0; p < 8; ++p) {
    float4 a = s_pos4[t + (2 * p) * 256];
    float4 c = s_pos4[t + (2 * p + 1) * 256];
    npx[p] = (f32x2){-a.x, -c.x};
    npy[p] = (f32x2){-a.y, -c.y};
    npz[p] = (f32x2){-a.z, -c.z};
    dist2[p] = (f32x2){__builtin_inff(), __builtin_inff()};
  }
  const int w = t >> 6, lane = t & 63;
  float sx = s_pos4[0].x, sy = s_pos4[0].y, sz = s_pos4[0].z;

  for (int m = 1; m < MS; ++m) {
    float bd = -1.0f;
    int bi = 0;
    f32x2 sxx = (f32x2){sx, sx}, syy = (f32x2){sy, sy}, szz = (f32x2){sz, sz};
#pragma unroll
    for (int p = 0; p < 8; ++p) {
      f32x2 dx = pk_add(sxx, npx[p]);      // sx - x (negation exact)
      f32x2 dy = pk_add(syy, npy[p]);
      f32x2 dz = pk_add(szz, npz[p]);
      f32x2 d2 = pk_add(pk_add(pk_mul(dx, dx), pk_mul(dy, dy)), pk_mul(dz, dz));
      float n0 = fminf(dist2[p][0], d2[0]);
      float n1 = fminf(dist2[p][1], d2[1]);
      dist2[p][0] = n0;
      dist2[p][1] = n1;
      // ascending visit order (j = 2p, 2p+1); strict > keeps lowest idx on tie
      if (n0 > bd) { bd = n0; bi = t + (2 * p) * 256; }
      if (n1 > bd) { bd = n1; bi = t + (2 * p + 1) * 256; }
    }
    // pack (dist_bits << 32) | ~idx : u64 max == max dist, tie -> min idx
    unsigned long long k =
        ((unsigned long long)__float_as_uint(bd) << 32) | (unsigned)(~bi);
    k = dpp_max_step<0x111, 0xF>(k);  // row_shr:1
    k = dpp_max_step<0x112, 0xF>(k);  // row_shr:2
    k = dpp_max_step<0x114, 0xF>(k);  // row_shr:4
    k = dpp_max_step<0x118, 0xF>(k);  // row_shr:8
    k = dpp_max_step<0x142, 0xA>(k);  // row_bcast15
    k = dpp_max_step<0x143, 0xC>(k);  // row_bcast31 -> lane63 = wave max
    const int par = m & 1;
    if (lane == 63) s_red[par][w] = k;
    __syncthreads();
    ulonglong2 ab = *reinterpret_cast<const ulonglong2*>(&s_red[par][0]);
    ulonglong2 cd = *reinterpret_cast<const ulonglong2*>(&s_red[par][2]);
    unsigned long long kb = u64max(u64max(ab.x, ab.y), u64max(cd.x, cd.y));
    const int nx = (int)(~(unsigned)(kb & 0xFFFFFFFFull));
    if (t == 0) idx_out[b * MS + m] = nx;
    float4 wp = s_pos4[nx];  // broadcast read
    sx = wp.x; sy = wp.y; sz = wp.z;
  }
}

// ---- radius(top-64) + MFMA-bf16 MLP + masked neighbor max (R3, proven) ----
__global__ __launch_bounds__(512, 4) void radconv_kernel(
    const float* __restrict__ x, const float* __restrict__ pos,
    const int* __restrict__ idx,
    const float* __restrict__ W1, const float* __restrict__ B1,
    const float* __restrict__ W2, const float* __restrict__ B2,
    const float* __restrict__ W3, const float* __restrict__ B3,
    float* __restrict__ out) {
  const int t = threadIdx.x;
  const int g = blockIdx.x >> 9;          // graph
  const int qpair = blockIdx.x & 511;     // 512 blocks/graph * 2 queries
  const float* pb = pos + (size_t)g * NPER * 3;
  const float* xb = x + (size_t)g * NPER * CIN;

  __shared__ int s_cnt[2];
  __shared__ float s_ctr[2][4];
  __shared__ __align__(16) unsigned long long s_list[2][LCAP];  // 6 KB
  __shared__ int s_nbr[2][64];
  __shared__ __align__(16) unsigned short sFeat[2][64 * 104];   // 26 KB (reused as red)
  __shared__ __align__(16) unsigned short sW1[64 * 104];        // 13 KB  [col][k<=96pad]
  __shared__ __align__(16) unsigned short sW2[64 * 72];         // 9 KB   [col][k=64+pad]
  __shared__ __align__(16) unsigned short sW3[128 * 72];        // 18 KB

  if (t < 2) s_cnt[t] = 0;
  const int q0 = g * MS + qpair * 2;
  const int qiA = idx[q0], qiB = idx[q0 + 1];
  const float cAx = pb[qiA * 3], cAy = pb[qiA * 3 + 1], cAz = pb[qiA * 3 + 2];
  const float cBx = pb[qiB * 3], cBy = pb[qiB * 3 + 1], cBz = pb[qiB * 3 + 2];
  if (t == 0) { s_ctr[0][0] = cAx; s_ctr[0][1] = cAy; s_ctr[0][2] = cAz; }
  if (t == 1) { s_ctr[1][0] = cBx; s_ctr[1][1] = cBy; s_ctr[1][2] = cBz; }
  __syncthreads();  // B1: s_cnt zeroed

  // ---- search: 8 pts/thread, both queries --------------------------------
  {
    float pp[24];
    const float4* pv = (const float4*)(pb + (size_t)t * 24);
#pragma unroll
    for (int r = 0; r < 6; ++r) {
      float4 v = pv[r];
      pp[r * 4 + 0] = v.x; pp[r * 4 + 1] = v.y;
      pp[r * 4 + 2] = v.z; pp[r * 4 + 3] = v.w;
    }
#pragma unroll
    for (int jj = 0; jj < 8; ++jj) {
      const int j = t * 8 + jj;
      const float X = pp[jj * 3], Y = pp[jj * 3 + 1], Z = pp[jj * 3 + 2];
      float dA = d2_exact(X, Y, Z, cAx, cAy, cAz);
      if (dA <= 0.04f) {  // f32(0.04) == JAX's R*R
        int p = atomicAdd(&s_cnt[0], 1);
        if (p < LCAP)
          s_list[0][p] = ((unsigned long long)__float_as_uint(dA) << 32) | (unsigned)j;
      }
      float dB = d2_exact(X, Y, Z, cBx, cBy, cBz);
      if (dB <= 0.04f) {
        int p = atomicAdd(&s_cnt[1], 1);
        if (p < LCAP)
          s_list[1][p] = ((unsigned long long)__float_as_uint(dB) << 32) | (unsigned)j;
      }
    }
  }
  // ---- stage weights (bf16, transposed) — independent of search ----------
  for (int ee = t; ee < 64 * 64; ee += 512) {           // zero W1 k-pad 67..103
    int c = ee >> 6, kk = 67 + (ee & 63);
    if (kk < 104) sW1[c * 104 + kk] = 0;
  }
  for (int e = t; e < 67 * 64; e += 512) {              // W1t[c][k] = W1[k][c]
    int k = e >> 6, c = e & 63;
    sW1[c * 104 + k] = f2bf(W1[e]);
  }
  for (int e = t; e < 64 * 64; e += 512) {
    int k = e >> 6, c = e & 63;
    sW2[c * 72 + k] = f2bf(W2[e]);
  }
  for (int e = t; e < 64 * 128; e += 512) {
    int k = e >> 7, c = e & 127;
    sW3[c * 72 + k] = f2bf(W3[e]);
  }
  __syncthreads();  // B2: lists + weights ready

  const int w = t >> 6, lane = t & 63;
  const int c0 = min(min(s_cnt[0], LCAP), 64);
  const int c1 = min(min(s_cnt[1], LCAP), 64);

  // ---- exact top-64 by (d2, idx) via rank; 4 waves per query -------------
  {
    const int rq = w >> 2;
    const int nsurv = min(s_cnt[rq], LCAP);
    for (int e = (w & 3) * 64 + lane; e < nsurv; e += 256) {
      unsigned long long mykey = s_list[rq][e];
      int rank = 0;
      int o = 0;
      for (; o + 8 <= nsurv; o += 8) {
        unsigned long long k0 = s_list[rq][o + 0], k1 = s_list[rq][o + 1];
        unsigned long long k2 = s_list[rq][o + 2], k3 = s_list[rq][o + 3];
        unsigned long long k4 = s_list[rq][o + 4], k5 = s_list[rq][o + 5];
        unsigned long long k6 = s_list[rq][o + 6], k7 = s_list[rq][o + 7];
        rank += (k0 < mykey) + (k1 < mykey) + (k2 < mykey) + (k3 < mykey) +
                (k4 < mykey) + (k5 < mykey) + (k6 < mykey) + (k7 < mykey);
      }
      for (; o < nsurv; ++o) rank += (s_list[rq][o] < mykey) ? 1 : 0;
      if (rank < 64) s_nbr[rq][rank] = (int)(mykey & 0xFFFFFFFFull);
    }
  }
  __syncthreads();  // B3: nbr lists ready

  // ---- gather feat rows: [x_j bf16 (64) | rel (3) | 0 pad ... 96) --------
  {
    const int slot = t >> 2, part = t & 3;   // 128 slots x 4 parts
    const int gq = slot >> 6, s = slot & 63;
    const int cq = gq ? c1 : c0;
    unsigned short* frow = &sFeat[gq][s * 104];
    uint4 z; z.x = z.y = z.z = z.w = 0u;
    if (s < cq) {
      const int j = s_nbr[gq][s];
      const float4* xr = (const float4*)(xb + (size_t)j * CIN + part * 16);
      float4 v0 = xr[0], v1 = xr[1], v2 = xr[2], v3 = xr[3];
      uint4 w0, w1;
      w0.x = f2bf(v0.x) | ((unsigned)f2bf(v0.y) << 16);
      w0.y = f2bf(v0.z) | ((unsigned)f2bf(v0.w) << 16);
      w0.z = f2bf(v1.x) | ((unsigned)f2bf(v1.y) << 16);
      w0.w = f2bf(v1.z) | ((unsigned)f2bf(v1.w) << 16);
      w1.x = f2bf(v2.x) | ((unsigned)f2bf(v2.y) << 16);
      w1.y = f2bf(v2.z) | ((unsigned)f2bf(v2.w) << 16);
      w1.z = f2bf(v3.x) | ((unsigned)f2bf(v3.y) << 16);
      w1.w = f2bf(v3.z) | ((unsigned)f2bf(v3.w) << 16);
      *(uint4*)(frow + part * 16) = w0;
      *(uint4*)(frow + part * 16 + 8) = w1;
      uint4 rz = z;
      if (part == 0) {
        const float cx = gq ? cBx : cAx, cy = gq ? cBy : cAy, cz = gq ? cBz : cAz;
        rz.x = f2bf(pb[j * 3] - cx) | ((unsigned)f2bf(pb[j * 3 + 1] - cy) << 16);
        rz.y = (unsigned)f2bf(pb[j * 3 + 2] - cz);
      }
      *(uint4*)(frow + 64 + part * 8) = rz;
    } else {
      *(uint4*)(frow + part * 16) = z;
      *(uint4*)(frow + part * 16 + 8) = z;
      *(uint4*)(frow + 64 + part * 8) = z;
    }
  }
  __syncthreads();  // B4: feat ready

  // ---- MFMA MLP: wave -> (query qq2, row tile mt) ------------------------
  const int qq2 = w >> 2;
  const int mt = w & 3;
  const int lo = lane & 15, hi = lane >> 4;
  unsigned short* F = &sFeat[qq2][0];
  const int arow = (16 * mt + lo) * 104;
  const int hrow = (16 * mt + hi * 4) * 104;

  {  // layer 1: K=96 (3 steps), N=64
    f32x4 acc[4];
#pragma unroll
    for (int n = 0; n < 4; ++n) {
      float bb = B1[n * 16 + lo];
      acc[n] = (f32x4){bb, bb, bb, bb};
    }
    s16x8 a0 = *(const s16x8*)(F + arow + 0 + hi * 8);
    s16x8 a1 = *(const s16x8*)(F + arow + 32 + hi * 8);
    s16x8 a2 = *(const s16x8*)(F + arow + 64 + hi * 8);
#pragma unroll
    for (int n = 0; n < 4; ++n) {
      const unsigned short* Bp = &sW1[(n * 16 + lo) * 104 + hi * 8];
      s16x8 b0 = *(const s16x8*)(Bp);
      s16x8 b1 = *(const s16x8*)(Bp + 32);
      s16x8 b2 = *(const s16x8*)(Bp + 64);
      acc[n] = __builtin_amdgcn_mfma_f32_16x16x32_bf16(a0, b0, acc[n], 0, 0, 0);
      acc[n] = __builtin_amdgcn_mfma_f32_16x16x32_bf16(a1, b1, acc[n], 0, 0, 0);
      acc[n] = __builtin_amdgcn_mfma_f32_16x16x32_bf16(a2, b2, acc[n], 0, 0, 0);
    }
#pragma unroll
    for (int n = 0; n < 4; ++n)
#pragma unroll
      for (int r = 0; r < 4; ++r)
        F[hrow + r * 104 + n * 16 + lo] = f2bf(fmaxf(acc[n][r], 0.f));
  }
  {  // layer 2: K=64 (2 steps), N=64
    f32x4 acc[4];
#pragma unroll
    for (int n = 0; n < 4; ++n) {
      float bb = B2[n * 16 + lo];
      acc[n] = (f32x4){bb, bb, bb, bb};
    }
    s16x8 a0 = *(const s16x8*)(F + arow + 0 + hi * 8);
    s16x8 a1 = *(const s16x8*)(F + arow + 32 + hi * 8);
#pragma unroll
    for (int n = 0; n < 4; ++n) {
      const unsigned short* Bp = &sW2[(n * 16 + lo) * 72 + hi * 8];
      s16x8 b0 = *(const s16x8*)(Bp);
      s16x8 b1 = *(const s16x8*)(Bp + 32);
      acc[n] = __builtin_amdgcn_mfma_f32_16x16x32_bf16(a0, b0, acc[n], 0, 0, 0);
      acc[n] = __builtin_amdgcn_mfma_f32_16x16x32_bf16(a1, b1, acc[n], 0, 0, 0);
    }
#pragma unroll
    for (int n = 0; n < 4; ++n)
#pragma unroll
      for (int r = 0; r < 4; ++r)
        F[hrow + r * 104 + n * 16 + lo] = f2bf(fmaxf(acc[n][r], 0.f));
  }
  float pm[8];
  {  // layer 3: K=64 (2 steps), N=128, fused masked row-max
    const int cq = qq2 ? c1 : c0;
    f32x4 acc[8];
#pragma unroll
    for (int n = 0; n < 8; ++n) {
      float bb = B3[n * 16 + lo];
      acc[n] = (f32x4){bb, bb, bb, bb};
    }
    s16x8 a0 = *(const s16x8*)(F + arow + 0 + hi * 8);
    s16x8 a1 = *(const s16x8*)(F + arow + 32 + hi * 8);
#pragma unroll
    for (int n = 0; n < 8; ++n) {
      const unsigned short* Bp = &sW3[(n * 16 + lo) * 72 + hi * 8];
      s16x8 b0 = *(const s16x8*)(Bp);
      s16x8 b1 = *(const s16x8*)(Bp + 32);
      acc[n] = __builtin_amdgcn_mfma_f32_16x16x32_bf16(a0, b0, acc[n], 0, 0, 0);
      acc[n] = __builtin_amdgcn_mfma_f32_16x16x32_bf16(a1, b1, acc[n], 0, 0, 0);
    }
#pragma unroll
    for (int n = 0; n < 8; ++n) {
      float v = -1e30f;
#pragma unroll
      for (int r = 0; r < 4; ++r) {
        int row = 16 * mt + hi * 4 + r;
        if (row < cq) v = fmaxf(v, fmaxf(acc[n][r], 0.f));
      }
      pm[n] = v;
    }
  }
  __syncthreads();  // B5: all sFeat reads done -> reuse as reduction buffer

  float* red = (float*)&sFeat[0][0];  // [2][128][17] floats
#pragma unroll
  for (int n = 0; n < 8; ++n)
    red[((qq2 * 128) + n * 16 + lo) * 17 + mt * 4 + hi] = pm[n];
  __syncthreads();  // B6

  if (t < 256) {
    const int gq = t >> 7, cc = t & 127;
    const float* rp = red + (gq * 128 + cc) * 17;
    float v = rp[0];
#pragma unroll
    for (int p = 1; p < 16; ++p) v = fmaxf(v, rp[p]);
    out[(size_t)(q0 + gq) * 128 + cc] = v;
  }
  if (t == 256 || t == 257) {
    const int gq = t - 256;
    const int qrow = q0 + gq;
    out[524288 + qrow * 3 + 0] = s_ctr[gq][0];
    out[524288 + qrow * 3 + 1] = s_ctr[gq][1];
    out[524288 + qrow * 3 + 2] = s_ctr[gq][2];
    out[536576 + qrow] = (float)g;
  }
}

extern "C" void kernel_launch(void* const* d_in, const int* in_sizes, int n_in,
                              void* d_out, int out_size, void* d_ws, size_t ws_size,
                              hipStream_t stream) {
  const float* x   = (const float*)d_in[0];
  const float* pos = (const float*)d_in[1];
  const float* W1  = (const float*)d_in[3];
  const float* B1  = (const float*)d_in[4];
  const float* W2  = (const float*)d_in[5];
  const float* B2  = (const float*)d_in[6];
  const float* W3  = (const float*)d_in[7];
  const float* B3  = (const float*)d_in[8];
  float* out = (float*)d_out;
  int* idx = (int*)d_ws;  // 4096 ints

  fps_kernel<<<4, 256, 0, stream>>>(pos, idx);
  radconv_kernel<<<2048, 512, 0, stream>>>(x, pos, idx, W1, B1, W2, B2, W3, B3, out);
}

// Round 8
// 681.843 us; speedup vs baseline: 1.1683x; 1.0202x over previous
//
#include <hip/hip_runtime.h>

#define NPER 4096
#define MS   1024
#define CIN  64
#define LCAP 384

typedef float  f32x4 __attribute__((ext_vector_type(4)));
typedef short  s16x8 __attribute__((ext_vector_type(8)));

// Exact d2 matching XLA: sub, rounded squares, left-assoc sum; no fma.
__device__ __forceinline__ float d2_exact(float ax, float ay, float az,
                                          float bx, float by, float bz) {
  float dx = __fsub_rn(ax, bx);
  float dy = __fsub_rn(ay, by);
  float dz = __fsub_rn(az, bz);
  return __fadd_rn(__fadd_rn(__fmul_rn(dx, dx), __fmul_rn(dy, dy)), __fmul_rn(dz, dz));
}

__device__ __forceinline__ unsigned short f2bf(float f) {
  unsigned b = __float_as_uint(f);
  return (unsigned short)((b + 0x7FFFu + ((b >> 16) & 1u)) >> 16);
}

template <int CTRL, int RMASK>
__device__ __forceinline__ unsigned long long dpp_max_step(unsigned long long k) {
  int hi = (int)(unsigned)(k >> 32);
  int lo = (int)(unsigned)(k & 0xFFFFFFFFull);
  int thi = __builtin_amdgcn_update_dpp(hi, hi, CTRL, RMASK, 0xF, false);
  int tlo = __builtin_amdgcn_update_dpp(lo, lo, CTRL, RMASK, 0xF, false);
  unsigned long long t =
      ((unsigned long long)(unsigned)thi << 32) | (unsigned)tlo;
  return t > k ? t : k;
}

__device__ __forceinline__ unsigned long long u64max(unsigned long long a,
                                                    unsigned long long b) {
  return a > b ? a : b;
}

// ---------------- FPS: one block per graph, 256 threads ---------------------
// R2-proven structure (597 us). Change vs R2: the 16-step linear argmax chain
// (VCC-serialized cmp+cndmask+cndmask per point) is restructured as a 4x4
// tournament: 4 independent chains (ILP, distinct compare dests) + 3 merges.
// Selection is provably identical: within-chain ascending strict-'>' keeps the
// first max; merges prefer left, and left chains own lower indices.
__global__ __launch_bounds__(256) void fps_kernel(const float* __restrict__ pos,
                                                  int* __restrict__ idx_out) {
  const int b = blockIdx.x;
  const int t = threadIdx.x;
  __shared__ float4 s_pos4[NPER];                       // 64 KB
  __shared__ __align__(16) unsigned long long s_red[2][4];
  const float* pb = pos + (size_t)b * NPER * 3;
  for (int i = t; i < NPER; i += 256)
    s_pos4[i] = make_float4(pb[i * 3], pb[i * 3 + 1], pb[i * 3 + 2], 0.f);
  if (t == 0) idx_out[b * MS] = 0;
  __syncthreads();

  float px[16], py[16], pz[16], dist[16];
#pragma unroll
  for (int j = 0; j < 16; ++j) {
    float4 p = s_pos4[t + j * 256];
    px[j] = p.x; py[j] = p.y; pz[j] = p.z;
    dist[j] = __builtin_inff();
  }
  const int w = t >> 6, lane = t & 63;
  float sx = s_pos4[0].x, sy = s_pos4[0].y, sz = s_pos4[0].z;

  for (int m = 1; m < MS; ++m) {
    // --- 4 independent argmax chains over 4 points each (ILP=4) -----------
    float bd0 = -1.f, bd1 = -1.f, bd2 = -1.f, bd3 = -1.f;
    int bi0 = 0, bi1 = 0, bi2 = 0, bi3 = 0;
#pragma unroll
    for (int k = 0; k < 4; ++k) {
      {  // chain 0: jj = k (indices t + k*256, ascending)
        const int j = k;
        float d2 = d2_exact(px[j], py[j], pz[j], sx, sy, sz);
        float nd = fminf(dist[j], d2);
        dist[j] = nd;
        if (nd > bd0) { bd0 = nd; bi0 = t + j * 256; }
      }
      {  // chain 1: jj = 4 + k
        const int j = 4 + k;
        float d2 = d2_exact(px[j], py[j], pz[j], sx, sy, sz);
        float nd = fminf(dist[j], d2);
        dist[j] = nd;
        if (nd > bd1) { bd1 = nd; bi1 = t + j * 256; }
      }
      {  // chain 2: jj = 8 + k
        const int j = 8 + k;
        float d2 = d2_exact(px[j], py[j], pz[j], sx, sy, sz);
        float nd = fminf(dist[j], d2);
        dist[j] = nd;
        if (nd > bd2) { bd2 = nd; bi2 = t + j * 256; }
      }
      {  // chain 3: jj = 12 + k
        const int j = 12 + k;
        float d2 = d2_exact(px[j], py[j], pz[j], sx, sy, sz);
        float nd = fminf(dist[j], d2);
        dist[j] = nd;
        if (nd > bd3) { bd3 = nd; bi3 = t + j * 256; }
      }
    }
    // --- merge (left-priority on ties == lowest index wins) ---------------
    if (bd1 > bd0) { bd0 = bd1; bi0 = bi1; }
    if (bd3 > bd2) { bd2 = bd3; bi2 = bi3; }
    if (bd2 > bd0) { bd0 = bd2; bi0 = bi2; }

    // pack (dist_bits << 32) | ~idx : u64 max == max dist, tie -> min idx
    unsigned long long k =
        ((unsigned long long)__float_as_uint(bd0) << 32) | (unsigned)(~bi0);
    k = dpp_max_step<0x111, 0xF>(k);  // row_shr:1
    k = dpp_max_step<0x112, 0xF>(k);  // row_shr:2
    k = dpp_max_step<0x114, 0xF>(k);  // row_shr:4
    k = dpp_max_step<0x118, 0xF>(k);  // row_shr:8
    k = dpp_max_step<0x142, 0xA>(k);  // row_bcast15
    k = dpp_max_step<0x143, 0xC>(k);  // row_bcast31 -> lane63 = wave max
    const int par = m & 1;
    if (lane == 63) s_red[par][w] = k;
    __syncthreads();
    ulonglong2 ab = *reinterpret_cast<const ulonglong2*>(&s_red[par][0]);
    ulonglong2 cd = *reinterpret_cast<const ulonglong2*>(&s_red[par][2]);
    unsigned long long kb = u64max(u64max(ab.x, ab.y), u64max(cd.x, cd.y));
    const int nx = (int)(~(unsigned)(kb & 0xFFFFFFFFull));
    if (t == 0) idx_out[b * MS + m] = nx;
    float4 wp = s_pos4[nx];  // broadcast read
    sx = wp.x; sy = wp.y; sz = wp.z;
  }
}

// ---- radius(top-64) + MFMA-bf16 MLP + masked neighbor max (R3, proven) ----
__global__ __launch_bounds__(512, 4) void radconv_kernel(
    const float* __restrict__ x, const float* __restrict__ pos,
    const int* __restrict__ idx,
    const float* __restrict__ W1, const float* __restrict__ B1,
    const float* __restrict__ W2, const float* __restrict__ B2,
    const float* __restrict__ W3, const float* __restrict__ B3,
    float* __restrict__ out) {
  const int t = threadIdx.x;
  const int g = blockIdx.x >> 9;          // graph
  const int qpair = blockIdx.x & 511;     // 512 blocks/graph * 2 queries
  const float* pb = pos + (size_t)g * NPER * 3;
  const float* xb = x + (size_t)g * NPER * CIN;

  __shared__ int s_cnt[2];
  __shared__ float s_ctr[2][4];
  __shared__ __align__(16) unsigned long long s_list[2][LCAP];  // 6 KB
  __shared__ int s_nbr[2][64];
  __shared__ __align__(16) unsigned short sFeat[2][64 * 104];   // 26 KB (reused as red)
  __shared__ __align__(16) unsigned short sW1[64 * 104];        // 13 KB  [col][k<=96pad]
  __shared__ __align__(16) unsigned short sW2[64 * 72];         // 9 KB   [col][k=64+pad]
  __shared__ __align__(16) unsigned short sW3[128 * 72];        // 18 KB

  if (t < 2) s_cnt[t] = 0;
  const int q0 = g * MS + qpair * 2;
  const int qiA = idx[q0], qiB = idx[q0 + 1];
  const float cAx = pb[qiA * 3], cAy = pb[qiA * 3 + 1], cAz = pb[qiA * 3 + 2];
  const float cBx = pb[qiB * 3], cBy = pb[qiB * 3 + 1], cBz = pb[qiB * 3 + 2];
  if (t == 0) { s_ctr[0][0] = cAx; s_ctr[0][1] = cAy; s_ctr[0][2] = cAz; }
  if (t == 1) { s_ctr[1][0] = cBx; s_ctr[1][1] = cBy; s_ctr[1][2] = cBz; }
  __syncthreads();  // B1: s_cnt zeroed

  // ---- search: 8 pts/thread, both queries --------------------------------
  {
    float pp[24];
    const float4* pv = (const float4*)(pb + (size_t)t * 24);
#pragma unroll
    for (int r = 0; r < 6; ++r) {
      float4 v = pv[r];
      pp[r * 4 + 0] = v.x; pp[r * 4 + 1] = v.y;
      pp[r * 4 + 2] = v.z; pp[r * 4 + 3] = v.w;
    }
#pragma unroll
    for (int jj = 0; jj < 8; ++jj) {
      const int j = t * 8 + jj;
      const float X = pp[jj * 3], Y = pp[jj * 3 + 1], Z = pp[jj * 3 + 2];
      float dA = d2_exact(X, Y, Z, cAx, cAy, cAz);
      if (dA <= 0.04f) {  // f32(0.04) == JAX's R*R
        int p = atomicAdd(&s_cnt[0], 1);
        if (p < LCAP)
          s_list[0][p] = ((unsigned long long)__float_as_uint(dA) << 32) | (unsigned)j;
      }
      float dB = d2_exact(X, Y, Z, cBx, cBy, cBz);
      if (dB <= 0.04f) {
        int p = atomicAdd(&s_cnt[1], 1);
        if (p < LCAP)
          s_list[1][p] = ((unsigned long long)__float_as_uint(dB) << 32) | (unsigned)j;
      }
    }
  }
  // ---- stage weights (bf16, transposed) — independent of search ----------
  for (int ee = t; ee < 64 * 64; ee += 512) {           // zero W1 k-pad 67..103
    int c = ee >> 6, kk = 67 + (ee & 63);
    if (kk < 104) sW1[c * 104 + kk] = 0;
  }
  for (int e = t; e < 67 * 64; e += 512) {              // W1t[c][k] = W1[k][c]
    int k = e >> 6, c = e & 63;
    sW1[c * 104 + k] = f2bf(W1[e]);
  }
  for (int e = t; e < 64 * 64; e += 512) {
    int k = e >> 6, c = e & 63;
    sW2[c * 72 + k] = f2bf(W2[e]);
  }
  for (int e = t; e < 64 * 128; e += 512) {
    int k = e >> 7, c = e & 127;
    sW3[c * 72 + k] = f2bf(W3[e]);
  }
  __syncthreads();  // B2: lists + weights ready

  const int w = t >> 6, lane = t & 63;
  const int c0 = min(min(s_cnt[0], LCAP), 64);
  const int c1 = min(min(s_cnt[1], LCAP), 64);

  // ---- exact top-64 by (d2, idx) via rank; 4 waves per query -------------
  {
    const int rq = w >> 2;
    const int nsurv = min(s_cnt[rq], LCAP);
    for (int e = (w & 3) * 64 + lane; e < nsurv; e += 256) {
      unsigned long long mykey = s_list[rq][e];
      int rank = 0;
      int o = 0;
      for (; o + 8 <= nsurv; o += 8) {
        unsigned long long k0 = s_list[rq][o + 0], k1 = s_list[rq][o + 1];
        unsigned long long k2 = s_list[rq][o + 2], k3 = s_list[rq][o + 3];
        unsigned long long k4 = s_list[rq][o + 4], k5 = s_list[rq][o + 5];
        unsigned long long k6 = s_list[rq][o + 6], k7 = s_list[rq][o + 7];
        rank += (k0 < mykey) + (k1 < mykey) + (k2 < mykey) + (k3 < mykey) +
                (k4 < mykey) + (k5 < mykey) + (k6 < mykey) + (k7 < mykey);
      }
      for (; o < nsurv; ++o) rank += (s_list[rq][o] < mykey) ? 1 : 0;
      if (rank < 64) s_nbr[rq][rank] = (int)(mykey & 0xFFFFFFFFull);
    }
  }
  __syncthreads();  // B3: nbr lists ready

  // ---- gather feat rows: [x_j bf16 (64) | rel (3) | 0 pad ... 96) --------
  {
    const int slot = t >> 2, part = t & 3;   // 128 slots x 4 parts
    const int gq = slot >> 6, s = slot & 63;
    const int cq = gq ? c1 : c0;
    unsigned short* frow = &sFeat[gq][s * 104];
    uint4 z; z.x = z.y = z.z = z.w = 0u;
    if (s < cq) {
      const int j = s_nbr[gq][s];
      const float4* xr = (const float4*)(xb + (size_t)j * CIN + part * 16);
      float4 v0 = xr[0], v1 = xr[1], v2 = xr[2], v3 = xr[3];
      uint4 w0, w1;
      w0.x = f2bf(v0.x) | ((unsigned)f2bf(v0.y) << 16);
      w0.y = f2bf(v0.z) | ((unsigned)f2bf(v0.w) << 16);
      w0.z = f2bf(v1.x) | ((unsigned)f2bf(v1.y) << 16);
      w0.w = f2bf(v1.z) | ((unsigned)f2bf(v1.w) << 16);
      w1.x = f2bf(v2.x) | ((unsigned)f2bf(v2.y) << 16);
      w1.y = f2bf(v2.z) | ((unsigned)f2bf(v2.w) << 16);
      w1.z = f2bf(v3.x) | ((unsigned)f2bf(v3.y) << 16);
      w1.w = f2bf(v3.z) | ((unsigned)f2bf(v3.w) << 16);
      *(uint4*)(frow + part * 16) = w0;
      *(uint4*)(frow + part * 16 + 8) = w1;
      uint4 rz = z;
      if (part == 0) {
        const float cx = gq ? cBx : cAx, cy = gq ? cBy : cAy, cz = gq ? cBz : cAz;
        rz.x = f2bf(pb[j * 3] - cx) | ((unsigned)f2bf(pb[j * 3 + 1] - cy) << 16);
        rz.y = (unsigned)f2bf(pb[j * 3 + 2] - cz);
      }
      *(uint4*)(frow + 64 + part * 8) = rz;
    } else {
      *(uint4*)(frow + part * 16) = z;
      *(uint4*)(frow + part * 16 + 8) = z;
      *(uint4*)(frow + 64 + part * 8) = z;
    }
  }
  __syncthreads();  // B4: feat ready

  // ---- MFMA MLP: wave -> (query qq2, row tile mt) ------------------------
  const int qq2 = w >> 2;
  const int mt = w & 3;
  const int lo = lane & 15, hi = lane >> 4;
  unsigned short* F = &sFeat[qq2][0];
  const int arow = (16 * mt + lo) * 104;
  const int hrow = (16 * mt + hi * 4) * 104;

  {  // layer 1: K=96 (3 steps), N=64
    f32x4 acc[4];
#pragma unroll
    for (int n = 0; n < 4; ++n) {
      float bb = B1[n * 16 + lo];
      acc[n] = (f32x4){bb, bb, bb, bb};
    }
    s16x8 a0 = *(const s16x8*)(F + arow + 0 + hi * 8);
    s16x8 a1 = *(const s16x8*)(F + arow + 32 + hi * 8);
    s16x8 a2 = *(const s16x8*)(F + arow + 64 + hi * 8);
#pragma unroll
    for (int n = 0; n < 4; ++n) {
      const unsigned short* Bp = &sW1[(n * 16 + lo) * 104 + hi * 8];
      s16x8 b0 = *(const s16x8*)(Bp);
      s16x8 b1 = *(const s16x8*)(Bp + 32);
      s16x8 b2 = *(const s16x8*)(Bp + 64);
      acc[n] = __builtin_amdgcn_mfma_f32_16x16x32_bf16(a0, b0, acc[n], 0, 0, 0);
      acc[n] = __builtin_amdgcn_mfma_f32_16x16x32_bf16(a1, b1, acc[n], 0, 0, 0);
      acc[n] = __builtin_amdgcn_mfma_f32_16x16x32_bf16(a2, b2, acc[n], 0, 0, 0);
    }
#pragma unroll
    for (int n = 0; n < 4; ++n)
#pragma unroll
      for (int r = 0; r < 4; ++r)
        F[hrow + r * 104 + n * 16 + lo] = f2bf(fmaxf(acc[n][r], 0.f));
  }
  {  // layer 2: K=64 (2 steps), N=64
    f32x4 acc[4];
#pragma unroll
    for (int n = 0; n < 4; ++n) {
      float bb = B2[n * 16 + lo];
      acc[n] = (f32x4){bb, bb, bb, bb};
    }
    s16x8 a0 = *(const s16x8*)(F + arow + 0 + hi * 8);
    s16x8 a1 = *(const s16x8*)(F + arow + 32 + hi * 8);
#pragma unroll
    for (int n = 0; n < 4; ++n) {
      const unsigned short* Bp = &sW2[(n * 16 + lo) * 72 + hi * 8];
      s16x8 b0 = *(const s16x8*)(Bp);
      s16x8 b1 = *(const s16x8*)(Bp + 32);
      acc[n] = __builtin_amdgcn_mfma_f32_16x16x32_bf16(a0, b0, acc[n], 0, 0, 0);
      acc[n] = __builtin_amdgcn_mfma_f32_16x16x32_bf16(a1, b1, acc[n], 0, 0, 0);
    }
#pragma unroll
    for (int n = 0; n < 4; ++n)
#pragma unroll
      for (int r = 0; r < 4; ++r)
        F[hrow + r * 104 + n * 16 + lo] = f2bf(fmaxf(acc[n][r], 0.f));
  }
  float pm[8];
  {  // layer 3: K=64 (2 steps), N=128, fused masked row-max
    const int cq = qq2 ? c1 : c0;
    f32x4 acc[8];
#pragma unroll
    for (int n = 0; n < 8; ++n) {
      float bb = B3[n * 16 + lo];
      acc[n] = (f32x4){bb, bb, bb, bb};
    }
    s16x8 a0 = *(const s16x8*)(F + arow + 0 + hi * 8);
    s16x8 a1 = *(const s16x8*)(F + arow + 32 + hi * 8);
#pragma unroll
    for (int n = 0; n < 8; ++n) {
      const unsigned short* Bp = &sW3[(n * 16 + lo) * 72 + hi * 8];
      s16x8 b0 = *(const s16x8*)(Bp);
      s16x8 b1 = *(const s16x8*)(Bp + 32);
      acc[n] = __builtin_amdgcn_mfma_f32_16x16x32_bf16(a0, b0, acc[n], 0, 0, 0);
      acc[n] = __builtin_amdgcn_mfma_f32_16x16x32_bf16(a1, b1, acc[n], 0, 0, 0);
    }
#pragma unroll
    for (int n = 0; n < 8; ++n) {
      float v = -1e30f;
#pragma unroll
      for (int r = 0; r < 4; ++r) {
        int row = 16 * mt + hi * 4 + r;
        if (row < cq) v = fmaxf(v, fmaxf(acc[n][r], 0.f));
      }
      pm[n] = v;
    }
  }
  __syncthreads();  // B5: all sFeat reads done -> reuse as reduction buffer

  float* red = (float*)&sFeat[0][0];  // [2][128][17] floats
#pragma unroll
  for (int n = 0; n < 8; ++n)
    red[((qq2 * 128) + n * 16 + lo) * 17 + mt * 4 + hi] = pm[n];
  __syncthreads();  // B6

  if (t < 256) {
    const int gq = t >> 7, cc = t & 127;
    const float* rp = red + (gq * 128 + cc) * 17;
    float v = rp[0];
#pragma unroll
    for (int p = 1; p < 16; ++p) v = fmaxf(v, rp[p]);
    out[(size_t)(q0 + gq) * 128 + cc] = v;
  }
  if (t == 256 || t == 257) {
    const int gq = t - 256;
    const int qrow = q0 + gq;
    out[524288 + qrow * 3 + 0] = s_ctr[gq][0];
    out[524288 + qrow * 3 + 1] = s_ctr[gq][1];
    out[524288 + qrow * 3 + 2] = s_ctr[gq][2];
    out[536576 + qrow] = (float)g;
  }
}

extern "C" void kernel_launch(void* const* d_in, const int* in_sizes, int n_in,
                              void* d_out, int out_size, void* d_ws, size_t ws_size,
                              hipStream_t stream) {
  const float* x   = (const float*)d_in[0];
  const float* pos = (const float*)d_in[1];
  const float* W1  = (const float*)d_in[3];
  const float* B1  = (const float*)d_in[4];
  const float* W2  = (const float*)d_in[5];
  const float* B2  = (const float*)d_in[6];
  const float* W3  = (const float*)d_in[7];
  const float* B3  = (const float*)d_in[8];
  float* out = (float*)d_out;
  int* idx = (int*)d_ws;  // 4096 ints

  fps_kernel<<<4, 256, 0, stream>>>(pos, idx);
  radconv_kernel<<<2048, 512, 0, stream>>>(x, pos, idx, W1, B1, W2, B2, W3, B3, out);
}